// Round 3
// baseline (22.965 us; speedup 1.0000x reference)
//
#include <hip/hip_runtime.h>

#define S_LEN 512
#define H_DIM 768
#define BS_TOK 8192      // B*S
#define NCOLS 80         // 64 mlp + 2 proj + 14 zero-pad
#define KSPLIT 4
#define KSEG 192         // H_DIM / KSPLIT
#define KPAD 200         // LDS B row stride (bf16 elems)
#define PSTRIDE 72       // fp16 partial row stride (144B)
#define BM 32            // rows per block (2 waves x 16)
#define TOKB 32          // tokens per block in fused epilogue kernel

typedef __attribute__((ext_vector_type(8))) short short8v;
typedef __attribute__((ext_vector_type(4))) short short4v;
typedef __attribute__((ext_vector_type(4))) float f32x4;
typedef __attribute__((ext_vector_type(4))) _Float16 h4;

__device__ __forceinline__ short f2bf(float f) {
  union { float f; unsigned u; } x; x.f = f;
  unsigned r = x.u + 0x7fffu + ((x.u >> 16) & 1u);
  return (short)(r >> 16);
}

// ===== k1: barrier-free(ish) MFMA GEMM, K split 4 ways, fp16 partial C =====
__global__ __launch_bounds__(128) void k1f(const float* __restrict__ hidden,
                                           const float* __restrict__ tw,
                                           const float* __restrict__ w1,
                                           const float* __restrict__ wsc,
                                           _Float16* __restrict__ part) {
  __shared__ short bs[NCOLS * KPAD];   // 32000 B
  const int tid  = threadIdx.x;
  const int bid  = blockIdx.x;
  const int tile = bid >> 2;           // 0..255
  const int kseg = bid & 3;
  const int k0   = kseg * KSEG;

  // stage B = [diag(tw)*w1 | w_score | 0], layout [col][k]
#pragma unroll
  for (int i = 0; i < 24; ++i) {
    int e = tid + 128 * i;             // 0..3071
    int koff = e >> 4, c4 = e & 15;
    int k = k0 + koff;
    float twk = tw[k];
    float4 w = *reinterpret_cast<const float4*>(w1 + (size_t)k * 64 + c4 * 4);
    bs[(c4 * 4 + 0) * KPAD + koff] = f2bf(w.x * twk);
    bs[(c4 * 4 + 1) * KPAD + koff] = f2bf(w.y * twk);
    bs[(c4 * 4 + 2) * KPAD + koff] = f2bf(w.z * twk);
    bs[(c4 * 4 + 3) * KPAD + koff] = f2bf(w.w * twk);
  }
#pragma unroll
  for (int i = 0; i < 3; ++i) {
    int e = tid + 128 * i;
    if (e < 2 * KSEG) {
      int koff = e >> 1, c = e & 1;
      bs[(64 + c) * KPAD + koff] = f2bf(wsc[(size_t)(k0 + koff) * 2 + c]);
    }
  }
  for (int i = tid; i < 14 * KSEG; i += 128) {
    int c = 66 + i / KSEG, koff = i - (c - 66) * KSEG;
    bs[c * KPAD + koff] = 0;
  }
  __syncthreads();   // the ONLY barrier

  const int w    = tid >> 6;
  const int lane = tid & 63;
  const int ci   = lane & 15;
  const int g    = lane >> 4;
  const int kg   = g * 8;
  const int r0   = tile * BM + w * 16;

  f32x4 acc[5];
#pragma unroll
  for (int nt = 0; nt < 5; ++nt) acc[nt] = (f32x4){0.f, 0.f, 0.f, 0.f};

  const float* aptr = hidden + (size_t)(r0 + ci) * H_DIM + k0 + kg;
#pragma unroll
  for (int ks = 0; ks < KSEG; ks += 32) {
    float4 a0 = *reinterpret_cast<const float4*>(aptr + ks);
    float4 a1 = *reinterpret_cast<const float4*>(aptr + ks + 4);
    short8v av;
    av[0] = f2bf(a0.x); av[1] = f2bf(a0.y); av[2] = f2bf(a0.z); av[3] = f2bf(a0.w);
    av[4] = f2bf(a1.x); av[5] = f2bf(a1.y); av[6] = f2bf(a1.z); av[7] = f2bf(a1.w);
#pragma unroll
    for (int nt = 0; nt < 5; ++nt) {
      short8v bb = *reinterpret_cast<const short8v*>(&bs[(nt * 16 + ci) * KPAD + ks + kg]);
      acc[nt] = __builtin_amdgcn_mfma_f32_16x16x32_bf16(av, bb, acc[nt], 0, 0, 0);
    }
  }

  _Float16* pr = part + ((size_t)kseg * BS_TOK + r0) * PSTRIDE;
#pragma unroll
  for (int j = 0; j < 4; ++j) {
    int r = 4 * g + j;
#pragma unroll
    for (int nt = 0; nt < 4; ++nt)
      pr[r * PSTRIDE + nt * 16 + ci] = (_Float16)acc[nt][j];
    if (ci < 2) pr[r * PSTRIDE + 64 + ci] = (_Float16)acc[4][j];
  }
}

// ===== kB: fused partial-reduce + relu-MLP epilogue + prefix softmax =====
__global__ __launch_bounds__(256) void kB(const _Float16* __restrict__ part,
                                          const float* __restrict__ b1,
                                          const float* __restrict__ w2,
                                          const float* __restrict__ b2,
                                          const float* __restrict__ bsc,
                                          float* __restrict__ out) {
  __shared__ float lp[TOKB + 8][4];   // [logit, p0, p1, pad]
  const int tid  = threadIdx.x;
  const int t0   = blockIdx.x * TOKB;
  const int w    = tid >> 6;
  const int lane = tid & 63;
  const int ci   = lane & 15;
  const int grp  = lane >> 4;
  const int base = w * 4 + grp;       // 0..15 token-slot per pass

#pragma unroll
  for (int pass = 0; pass < 3; ++pass) {
    int slot = pass * 16 + base;
    if (slot < TOKB + 7) {
      int tt = min(t0 + slot, BS_TOK - 1);
      f32x4 s = (f32x4){0.f, 0.f, 0.f, 0.f};
#pragma unroll
      for (int seg = 0; seg < KSPLIT; ++seg) {
        h4 v = *reinterpret_cast<const h4*>(
            part + ((size_t)seg * BS_TOK + tt) * PSTRIDE + 4 * ci);
        s[0] += (float)v[0]; s[1] += (float)v[1];
        s[2] += (float)v[2]; s[3] += (float)v[3];
      }
      const float4 bb = *reinterpret_cast<const float4*>(b1 + 4 * ci);
      const float4 ww = *reinterpret_cast<const float4*>(w2 + 4 * ci);
      float r = fmaxf(s[0] + bb.x, 0.f) * ww.x + fmaxf(s[1] + bb.y, 0.f) * ww.y +
                fmaxf(s[2] + bb.z, 0.f) * ww.z + fmaxf(s[3] + bb.w, 0.f) * ww.w;
#pragma unroll
      for (int msk = 1; msk < 16; msk <<= 1) r += __shfl_xor(r, msk, 64);
      if (ci == 0) lp[slot][0] = r + b2[0];
      if (ci < 2) {
        float pv = 0.f;
#pragma unroll
        for (int seg = 0; seg < KSPLIT; ++seg)
          pv += (float)part[((size_t)seg * BS_TOK + tt) * PSTRIDE + 64 + ci];
        lp[slot][1 + ci] = pv;
      }
    }
  }
  __syncthreads();

  if (tid < TOKB) {
    int t = t0 + tid;
    int s_ = t & (S_LEN - 1);
    int nmax = min(8, S_LEN - s_);
    float bs0 = bsc[0], bs1 = bsc[1];
    float m = lp[tid][0];
    float d = 1.f;
    float n0 = lp[tid][1], n1 = lp[tid][2];
    float o[16];
    o[0] = n0 + bs0; o[1] = n1 + bs1;
#pragma unroll
    for (int j = 1; j < 8; ++j) {
      if (j < nmax) {
        float L  = lp[tid + j][0];
        float nm = fmaxf(m, L);
        float sc = __expf(m - nm);
        float e  = __expf(L - nm);
        d  = d  * sc + e;
        n0 = n0 * sc + e * lp[tid + j][1];
        n1 = n1 * sc + e * lp[tid + j][2];
        m = nm;
      }
      float inv = 1.f / d;
      o[2 * j]     = n0 * inv + bs0;
      o[2 * j + 1] = n1 * inv + bs1;
    }
    float4* op = reinterpret_cast<float4*>(out + (size_t)t * 16);
#pragma unroll
    for (int i = 0; i < 4; ++i) op[i] = *reinterpret_cast<float4*>(&o[4 * i]);
  }
}

// ===== fallback path (small ws; round-1 kernels) =====

__global__ __launch_bounds__(256) void kprep(const float* __restrict__ tw,
                                             const float* __restrict__ w1,
                                             const float* __restrict__ wsc,
                                             short* __restrict__ wcat) {
  int i = blockIdx.x * 256 + threadIdx.x;
  if (i >= NCOLS * H_DIM) return;
  int c = i / H_DIM, k = i - c * H_DIM;
  float v = 0.f;
  if (c < 64)       v = tw[k] * w1[k * 64 + c];
  else if (c == 64) v = wsc[k * 2 + 0];
  else if (c == 65) v = wsc[k * 2 + 1];
  wcat[i] = f2bf(v);
}

__global__ __launch_bounds__(256) void k1s(const float* __restrict__ hidden,
                                           const short* __restrict__ wcat,
                                           const float* __restrict__ b1,
                                           const float* __restrict__ w2,
                                           const float* __restrict__ b2,
                                           float* __restrict__ logit,
                                           float* __restrict__ pbuf) {
  __shared__ short as[64 * 72];
  __shared__ short bss[NCOLS * 72];
  const int tid  = threadIdx.x;
  const int t0   = blockIdx.x * 64;
  const int w    = tid >> 6;
  const int lane = tid & 63;
  const int ci   = lane & 15;
  const int kg   = (lane >> 4) * 8;
  const int arow = w * 16 + ci;

  f32x4 acc[5];
#pragma unroll
  for (int nt = 0; nt < 5; ++nt) acc[nt] = (f32x4){0.f, 0.f, 0.f, 0.f};

  for (int cc = 0; cc < H_DIM / 64; ++cc) {
    const int k0 = cc * 64;
    __syncthreads();
#pragma unroll
    for (int i = 0; i < 4; ++i) {
      int f = tid + 256 * i;
      int r = f >> 4, c4 = f & 15;
      const float4 v = *reinterpret_cast<const float4*>(
          hidden + (size_t)(t0 + r) * H_DIM + k0 + c4 * 4);
      short4v bv;
      bv[0] = f2bf(v.x); bv[1] = f2bf(v.y); bv[2] = f2bf(v.z); bv[3] = f2bf(v.w);
      *reinterpret_cast<short4v*>(&as[r * 72 + c4 * 4]) = bv;
    }
    for (int i = tid; i < NCOLS * 8; i += 256) {
      int r = i >> 3, c8 = i & 7;
      short8v v = *reinterpret_cast<const short8v*>(wcat + r * H_DIM + k0 + c8 * 8);
      *reinterpret_cast<short8v*>(&bss[r * 72 + c8 * 8]) = v;
    }
    __syncthreads();
#pragma unroll
    for (int ks = 0; ks < 64; ks += 32) {
      short8v a = *reinterpret_cast<const short8v*>(&as[arow * 72 + ks + kg]);
#pragma unroll
      for (int nt = 0; nt < 5; ++nt) {
        short8v bb = *reinterpret_cast<const short8v*>(&bss[(nt * 16 + ci) * 72 + ks + kg]);
        acc[nt] = __builtin_amdgcn_mfma_f32_16x16x32_bf16(a, bb, acc[nt], 0, 0, 0);
      }
    }
  }

  const int g = lane >> 4;
  float lg[4];
#pragma unroll
  for (int j = 0; j < 4; ++j) {
    float sacc = 0.f;
#pragma unroll
    for (int nt = 0; nt < 4; ++nt) {
      int c = nt * 16 + ci;
      float z = acc[nt][j] + b1[c];
      z = fmaxf(z, 0.f);
      sacc += z * w2[c];
    }
#pragma unroll
    for (int msk = 1; msk < 16; msk <<= 1) sacc += __shfl_xor(sacc, msk, 64);
    lg[j] = sacc;
  }
  const float b2v = b2[0];
#pragma unroll
  for (int j = 0; j < 4; ++j) {
    int rg = t0 + w * 16 + 4 * g + j;
    if (ci == 0) {
      logit[rg] = lg[j] + b2v;
      pbuf[rg * 2 + 0] = acc[4][j];
    } else if (ci == 1) {
      pbuf[rg * 2 + 1] = acc[4][j];
    }
  }
}

__global__ __launch_bounds__(256) void k3g(const float* __restrict__ logit,
                                           const float* __restrict__ pbuf,
                                           const float* __restrict__ bsc,
                                           float* __restrict__ out) {
  int t = blockIdx.x * 256 + threadIdx.x;
  int s = t & (S_LEN - 1);
  int nmax = min(8, S_LEN - s);
  float bs0 = bsc[0], bs1 = bsc[1];
  float m = logit[t];
  float d = 1.f;
  float n0 = pbuf[2 * t], n1 = pbuf[2 * t + 1];
  float o[16];
  o[0] = n0 + bs0; o[1] = n1 + bs1;
#pragma unroll
  for (int j = 1; j < 8; ++j) {
    if (j < nmax) {
      float L  = logit[t + j];
      float nm = fmaxf(m, L);
      float sc = __expf(m - nm);
      float e  = __expf(L - nm);
      d  = d  * sc + e;
      n0 = n0 * sc + e * pbuf[2 * (t + j)];
      n1 = n1 * sc + e * pbuf[2 * (t + j) + 1];
      m = nm;
    }
    float inv = 1.f / d;
    o[2 * j]     = n0 * inv + bs0;
    o[2 * j + 1] = n1 * inv + bs1;
  }
  float4* op = reinterpret_cast<float4*>(out + (size_t)t * 16);
#pragma unroll
  for (int i = 0; i < 4; ++i) op[i] = *reinterpret_cast<float4*>(&o[4 * i]);
}

// ===== launch =====

extern "C" void kernel_launch(void* const* d_in, const int* in_sizes, int n_in,
                              void* d_out, int out_size, void* d_ws, size_t ws_size,
                              hipStream_t stream) {
  const float* hidden = (const float*)d_in[0];
  const float* tw     = (const float*)d_in[1];
  const float* w1     = (const float*)d_in[2];
  const float* b1     = (const float*)d_in[3];
  const float* w2     = (const float*)d_in[4];
  const float* b2     = (const float*)d_in[5];
  const float* wsc    = (const float*)d_in[6];
  const float* bsc    = (const float*)d_in[7];
  float* out = (float*)d_out;
  char* ws = (char*)d_ws;

  const size_t part_bytes = (size_t)KSPLIT * BS_TOK * PSTRIDE * 2;  // 4,718,592

  if (ws_size >= part_bytes) {
    _Float16* part = (_Float16*)ws;
    k1f<<<(BS_TOK / BM) * KSPLIT, 128, 0, stream>>>(hidden, tw, w1, wsc, part);
    kB <<<BS_TOK / TOKB, 256, 0, stream>>>(part, b1, w2, b2, bsc, out);
  } else {
    short* wcat  = (short*)ws;
    float* logit = (float*)(ws + 131072);
    float* pbuf  = (float*)(ws + 131072 + 32768);
    kprep<<<(NCOLS * H_DIM + 255) / 256, 256, 0, stream>>>(tw, w1, wsc, wcat);
    k1s<<<BS_TOK / 64, 256, 0, stream>>>(hidden, wcat, b1, w2, b2, logit, pbuf);
    k3g<<<BS_TOK / 256, 256, 0, stream>>>(logit, pbuf, bsc, out);
  }
}

// Round 4
// 22.574 us; speedup vs baseline: 1.0173x; 1.0173x over previous
//
#include <hip/hip_runtime.h>

#define S_LEN 512
#define H_DIM 768
#define BS_TOK 8192      // B*S
#define NCOLS 80         // 64 mlp + 2 proj + 14 zero-pad
#define KSPLIT 4
#define KSEG 192         // H_DIM / KSPLIT
#define KPAD 200         // B row stride in bf16 elems (400B; (stride/4)%32=4, +8-elem pad idiom)
#define WSEG (NCOLS * KPAD)   // 16000 elems = 32000B per kseg
#define PSTRIDE 72       // fp16 partial row stride (144B)
#define BM 64            // rows per block (4 waves x 16)
#define TOKB 32          // tokens per block in fused epilogue kernel

typedef __attribute__((ext_vector_type(8))) short short8v;
typedef __attribute__((ext_vector_type(4))) short short4v;
typedef __attribute__((ext_vector_type(4))) float f32x4;
typedef __attribute__((ext_vector_type(4))) _Float16 h4;

__device__ __forceinline__ short f2bf(float f) {
  union { float f; unsigned u; } x; x.f = f;
  unsigned r = x.u + 0x7fffu + ((x.u >> 16) & 1u);
  return (short)(r >> 16);
}

// ===== kprep: build wcat_pad[KSPLIT][NCOLS][KPAD] bf16 — the exact k1 LDS image =====
// row c<64: tw[k]*w1[k][c]; c=64/65: w_score[:,c-64]; c>=66 or koff>=KSEG: 0
__global__ __launch_bounds__(256) void kprep(const float* __restrict__ tw,
                                             const float* __restrict__ w1,
                                             const float* __restrict__ wsc,
                                             short* __restrict__ wcat) {
  int i = blockIdx.x * 256 + threadIdx.x;
  if (i >= KSPLIT * WSEG) return;
  int kseg = i / WSEG;
  int rem  = i - kseg * WSEG;
  int c    = rem / KPAD;
  int koff = rem - c * KPAD;
  float v = 0.f;
  if (koff < KSEG && c < 66) {
    int k = kseg * KSEG + koff;
    if (c < 64) v = tw[k] * w1[(size_t)k * 64 + c];
    else        v = wsc[(size_t)k * 2 + (c - 64)];
  }
  wcat[i] = f2bf(v);
}

// ===== k1: single-barrier MFMA GEMM, K split 4 ways, fp16 partial C =====
__global__ __launch_bounds__(256) void k1f(const float* __restrict__ hidden,
                                           const short* __restrict__ wcat,
                                           _Float16* __restrict__ part) {
  __shared__ short bs[WSEG];           // 32000 B
  const int tid  = threadIdx.x;
  const int bid  = blockIdx.x;
  const int tile = bid >> 2;           // 0..127
  const int kseg = bid & 3;
  const int k0   = kseg * KSEG;

  // stage B: straight 16B copy of the precomputed LDS image (no transpose, no cvt)
  const short* wseg = wcat + (size_t)kseg * WSEG;
#pragma unroll
  for (int i = 0; i < 7; ++i) {
    int e = tid + 256 * i;             // 0..1791 vectors of 8
    *reinterpret_cast<short8v*>(&bs[e * 8]) =
        *reinterpret_cast<const short8v*>(wseg + (size_t)e * 8);
  }
  if (tid < 208) {
    int e = 1792 + tid;                // ..1999
    *reinterpret_cast<short8v*>(&bs[e * 8]) =
        *reinterpret_cast<const short8v*>(wseg + (size_t)e * 8);
  }
  __syncthreads();   // the ONLY barrier

  const int w    = tid >> 6;
  const int lane = tid & 63;
  const int ci   = lane & 15;
  const int g    = lane >> 4;
  const int kg   = g * 8;
  const int r0   = tile * BM + w * 16;

  f32x4 acc[5];
#pragma unroll
  for (int nt = 0; nt < 5; ++nt) acc[nt] = (f32x4){0.f, 0.f, 0.f, 0.f};

  const float* aptr = hidden + (size_t)(r0 + ci) * H_DIM + k0 + kg;
#pragma unroll
  for (int ks = 0; ks < KSEG; ks += 32) {
    float4 a0 = *reinterpret_cast<const float4*>(aptr + ks);
    float4 a1 = *reinterpret_cast<const float4*>(aptr + ks + 4);
    short8v av;
    av[0] = f2bf(a0.x); av[1] = f2bf(a0.y); av[2] = f2bf(a0.z); av[3] = f2bf(a0.w);
    av[4] = f2bf(a1.x); av[5] = f2bf(a1.y); av[6] = f2bf(a1.z); av[7] = f2bf(a1.w);
#pragma unroll
    for (int nt = 0; nt < 5; ++nt) {
      short8v bb = *reinterpret_cast<const short8v*>(&bs[(nt * 16 + ci) * KPAD + ks + kg]);
      acc[nt] = __builtin_amdgcn_mfma_f32_16x16x32_bf16(av, bb, acc[nt], 0, 0, 0);
    }
  }

  _Float16* pr = part + ((size_t)kseg * BS_TOK + r0) * PSTRIDE;
#pragma unroll
  for (int j = 0; j < 4; ++j) {
    int r = 4 * g + j;
#pragma unroll
    for (int nt = 0; nt < 4; ++nt)
      pr[r * PSTRIDE + nt * 16 + ci] = (_Float16)acc[nt][j];
    if (ci < 2) pr[r * PSTRIDE + 64 + ci] = (_Float16)acc[4][j];
  }
}

// ===== kB: fused partial-reduce + relu-MLP epilogue + prefix softmax =====
__global__ __launch_bounds__(256) void kB(const _Float16* __restrict__ part,
                                          const float* __restrict__ b1,
                                          const float* __restrict__ w2,
                                          const float* __restrict__ b2,
                                          const float* __restrict__ bsc,
                                          float* __restrict__ out) {
  __shared__ float lp[TOKB + 8][4];   // [logit, p0, p1, pad]
  const int tid  = threadIdx.x;
  const int t0   = blockIdx.x * TOKB;
  const int w    = tid >> 6;
  const int lane = tid & 63;
  const int ci   = lane & 15;
  const int grp  = lane >> 4;
  const int base = w * 4 + grp;       // 0..15 token-slot per pass

#pragma unroll
  for (int pass = 0; pass < 3; ++pass) {
    int slot = pass * 16 + base;
    if (slot < TOKB + 7) {
      int tt = min(t0 + slot, BS_TOK - 1);
      f32x4 s = (f32x4){0.f, 0.f, 0.f, 0.f};
#pragma unroll
      for (int seg = 0; seg < KSPLIT; ++seg) {
        h4 v = *reinterpret_cast<const h4*>(
            part + ((size_t)seg * BS_TOK + tt) * PSTRIDE + 4 * ci);
        s[0] += (float)v[0]; s[1] += (float)v[1];
        s[2] += (float)v[2]; s[3] += (float)v[3];
      }
      const float4 bb = *reinterpret_cast<const float4*>(b1 + 4 * ci);
      const float4 ww = *reinterpret_cast<const float4*>(w2 + 4 * ci);
      float r = fmaxf(s[0] + bb.x, 0.f) * ww.x + fmaxf(s[1] + bb.y, 0.f) * ww.y +
                fmaxf(s[2] + bb.z, 0.f) * ww.z + fmaxf(s[3] + bb.w, 0.f) * ww.w;
#pragma unroll
      for (int msk = 1; msk < 16; msk <<= 1) r += __shfl_xor(r, msk, 64);
      if (ci == 0) lp[slot][0] = r + b2[0];
      if (ci < 2) {
        float pv = 0.f;
#pragma unroll
        for (int seg = 0; seg < KSPLIT; ++seg)
          pv += (float)part[((size_t)seg * BS_TOK + tt) * PSTRIDE + 64 + ci];
        lp[slot][1 + ci] = pv;
      }
    }
  }
  __syncthreads();

  if (tid < TOKB) {
    int t = t0 + tid;
    int s_ = t & (S_LEN - 1);
    int nmax = min(8, S_LEN - s_);
    float bs0 = bsc[0], bs1 = bsc[1];
    float m = lp[tid][0];
    float d = 1.f;
    float n0 = lp[tid][1], n1 = lp[tid][2];
    float o[16];
    o[0] = n0 + bs0; o[1] = n1 + bs1;
#pragma unroll
    for (int j = 1; j < 8; ++j) {
      if (j < nmax) {
        float L  = lp[tid + j][0];
        float nm = fmaxf(m, L);
        float sc = __expf(m - nm);
        float e  = __expf(L - nm);
        d  = d  * sc + e;
        n0 = n0 * sc + e * lp[tid + j][1];
        n1 = n1 * sc + e * lp[tid + j][2];
        m = nm;
      }
      float inv = 1.f / d;
      o[2 * j]     = n0 * inv + bs0;
      o[2 * j + 1] = n1 * inv + bs1;
    }
    float4* op = reinterpret_cast<float4*>(out + (size_t)t * 16);
#pragma unroll
    for (int i = 0; i < 4; ++i) op[i] = *reinterpret_cast<float4*>(&o[4 * i]);
  }
}

// ===== fallback path (small ws; round-1 kernels) =====

__global__ __launch_bounds__(256) void kprepS(const float* __restrict__ tw,
                                              const float* __restrict__ w1,
                                              const float* __restrict__ wsc,
                                              short* __restrict__ wcat) {
  int i = blockIdx.x * 256 + threadIdx.x;
  if (i >= NCOLS * H_DIM) return;
  int c = i / H_DIM, k = i - c * H_DIM;
  float v = 0.f;
  if (c < 64)       v = tw[k] * w1[k * 64 + c];
  else if (c == 64) v = wsc[k * 2 + 0];
  else if (c == 65) v = wsc[k * 2 + 1];
  wcat[i] = f2bf(v);
}

__global__ __launch_bounds__(256) void k1s(const float* __restrict__ hidden,
                                           const short* __restrict__ wcat,
                                           const float* __restrict__ b1,
                                           const float* __restrict__ w2,
                                           const float* __restrict__ b2,
                                           float* __restrict__ logit,
                                           float* __restrict__ pbuf) {
  __shared__ short as[64 * 72];
  __shared__ short bss[NCOLS * 72];
  const int tid  = threadIdx.x;
  const int t0   = blockIdx.x * 64;
  const int w    = tid >> 6;
  const int lane = tid & 63;
  const int ci   = lane & 15;
  const int kg   = (lane >> 4) * 8;
  const int arow = w * 16 + ci;

  f32x4 acc[5];
#pragma unroll
  for (int nt = 0; nt < 5; ++nt) acc[nt] = (f32x4){0.f, 0.f, 0.f, 0.f};

  for (int cc = 0; cc < H_DIM / 64; ++cc) {
    const int k0 = cc * 64;
    __syncthreads();
#pragma unroll
    for (int i = 0; i < 4; ++i) {
      int f = tid + 256 * i;
      int r = f >> 4, c4 = f & 15;
      const float4 v = *reinterpret_cast<const float4*>(
          hidden + (size_t)(t0 + r) * H_DIM + k0 + c4 * 4);
      short4v bv;
      bv[0] = f2bf(v.x); bv[1] = f2bf(v.y); bv[2] = f2bf(v.z); bv[3] = f2bf(v.w);
      *reinterpret_cast<short4v*>(&as[r * 72 + c4 * 4]) = bv;
    }
    for (int i = tid; i < NCOLS * 8; i += 256) {
      int r = i >> 3, c8 = i & 7;
      short8v v = *reinterpret_cast<const short8v*>(wcat + r * H_DIM + k0 + c8 * 8);
      *reinterpret_cast<short8v*>(&bss[r * 72 + c8 * 8]) = v;
    }
    __syncthreads();
#pragma unroll
    for (int ks = 0; ks < 64; ks += 32) {
      short8v a = *reinterpret_cast<const short8v*>(&as[arow * 72 + ks + kg]);
#pragma unroll
      for (int nt = 0; nt < 5; ++nt) {
        short8v bb = *reinterpret_cast<const short8v*>(&bss[(nt * 16 + ci) * 72 + ks + kg]);
        acc[nt] = __builtin_amdgcn_mfma_f32_16x16x32_bf16(a, bb, acc[nt], 0, 0, 0);
      }
    }
  }

  const int g = lane >> 4;
  float lg[4];
#pragma unroll
  for (int j = 0; j < 4; ++j) {
    float sacc = 0.f;
#pragma unroll
    for (int nt = 0; nt < 4; ++nt) {
      int c = nt * 16 + ci;
      float z = acc[nt][j] + b1[c];
      z = fmaxf(z, 0.f);
      sacc += z * w2[c];
    }
#pragma unroll
    for (int msk = 1; msk < 16; msk <<= 1) sacc += __shfl_xor(sacc, msk, 64);
    lg[j] = sacc;
  }
  const float b2v = b2[0];
#pragma unroll
  for (int j = 0; j < 4; ++j) {
    int rg = t0 + w * 16 + 4 * g + j;
    if (ci == 0) {
      logit[rg] = lg[j] + b2v;
      pbuf[rg * 2 + 0] = acc[4][j];
    } else if (ci == 1) {
      pbuf[rg * 2 + 1] = acc[4][j];
    }
  }
}

__global__ __launch_bounds__(256) void k3g(const float* __restrict__ logit,
                                           const float* __restrict__ pbuf,
                                           const float* __restrict__ bsc,
                                           float* __restrict__ out) {
  int t = blockIdx.x * 256 + threadIdx.x;
  int s = t & (S_LEN - 1);
  int nmax = min(8, S_LEN - s);
  float bs0 = bsc[0], bs1 = bsc[1];
  float m = logit[t];
  float d = 1.f;
  float n0 = pbuf[2 * t], n1 = pbuf[2 * t + 1];
  float o[16];
  o[0] = n0 + bs0; o[1] = n1 + bs1;
#pragma unroll
  for (int j = 1; j < 8; ++j) {
    if (j < nmax) {
      float L  = logit[t + j];
      float nm = fmaxf(m, L);
      float sc = __expf(m - nm);
      float e  = __expf(L - nm);
      d  = d  * sc + e;
      n0 = n0 * sc + e * pbuf[2 * (t + j)];
      n1 = n1 * sc + e * pbuf[2 * (t + j) + 1];
      m = nm;
    }
    float inv = 1.f / d;
    o[2 * j]     = n0 * inv + bs0;
    o[2 * j + 1] = n1 * inv + bs1;
  }
  float4* op = reinterpret_cast<float4*>(out + (size_t)t * 16);
#pragma unroll
  for (int i = 0; i < 4; ++i) op[i] = *reinterpret_cast<float4*>(&o[4 * i]);
}

// ===== launch =====

extern "C" void kernel_launch(void* const* d_in, const int* in_sizes, int n_in,
                              void* d_out, int out_size, void* d_ws, size_t ws_size,
                              hipStream_t stream) {
  const float* hidden = (const float*)d_in[0];
  const float* tw     = (const float*)d_in[1];
  const float* w1     = (const float*)d_in[2];
  const float* b1     = (const float*)d_in[3];
  const float* w2     = (const float*)d_in[4];
  const float* b2     = (const float*)d_in[5];
  const float* wsc    = (const float*)d_in[6];
  const float* bsc    = (const float*)d_in[7];
  float* out = (float*)d_out;
  char* ws = (char*)d_ws;

  const size_t part_bytes = (size_t)KSPLIT * BS_TOK * PSTRIDE * 2;  // 4,718,592
  const size_t wcat_bytes = (size_t)KSPLIT * WSEG * 2;              // 128,000
  const size_t need_fast  = part_bytes + wcat_bytes;

  if (ws_size >= need_fast) {
    _Float16* part = (_Float16*)ws;
    short* wcat    = (short*)(ws + part_bytes);
    kprep<<<(KSPLIT * WSEG + 255) / 256, 256, 0, stream>>>(tw, w1, wsc, wcat);
    k1f  <<<(BS_TOK / BM) * KSPLIT, 256, 0, stream>>>(hidden, wcat, part);
    kB   <<<BS_TOK / TOKB, 256, 0, stream>>>(part, b1, w2, b2, bsc, out);
  } else {
    short* wcat  = (short*)ws;
    float* logit = (float*)(ws + 131072);
    float* pbuf  = (float*)(ws + 131072 + 32768);
    kprepS<<<(NCOLS * H_DIM + 255) / 256, 256, 0, stream>>>(tw, w1, wsc, wcat);
    k1s<<<BS_TOK / 64, 256, 0, stream>>>(hidden, wcat, b1, w2, b2, logit, pbuf);
    k3g<<<BS_TOK / 256, 256, 0, stream>>>(logit, pbuf, bsc, out);
  }
}

// Round 5
// 22.189 us; speedup vs baseline: 1.0350x; 1.0174x over previous
//
#include <hip/hip_runtime.h>

#define S_LEN 512
#define H_DIM 768
#define BS_TOK 8192      // B*S
#define NCOLS 80         // 64 mlp + 2 proj + 14 zero-pad
#define KSPLIT 4
#define KSEG 192         // H_DIM / KSPLIT
#define KPAD 200         // B row stride in bf16 elems (400B)
#define WSEG (NCOLS * KPAD)   // 16000 elems = 32000B per kseg
#define PSTRIDE 72       // fp16 partial row stride (144B)
#define BM 64            // rows per block (4 waves x 16)
#define TOKB 32          // tokens per block in fused epilogue kernel

typedef __attribute__((ext_vector_type(8))) short short8v;
typedef __attribute__((ext_vector_type(4))) short short4v;
typedef __attribute__((ext_vector_type(4))) float f32x4;
typedef __attribute__((ext_vector_type(4))) _Float16 h4;

__device__ __forceinline__ short f2bf(float f) {
  union { float f; unsigned u; } x; x.f = f;
  unsigned r = x.u + 0x7fffu + ((x.u >> 16) & 1u);
  return (short)(r >> 16);
}

// ===== kprep: build wcat_pad[KSPLIT][NCOLS][KPAD] bf16 — the exact k1 LDS image =====
__global__ __launch_bounds__(256) void kprep(const float* __restrict__ tw,
                                             const float* __restrict__ w1,
                                             const float* __restrict__ wsc,
                                             short* __restrict__ wcat) {
  int i = blockIdx.x * 256 + threadIdx.x;
  if (i >= KSPLIT * WSEG) return;
  int kseg = i / WSEG;
  int rem  = i - kseg * WSEG;
  int c    = rem / KPAD;
  int koff = rem - c * KPAD;
  float v = 0.f;
  if (koff < KSEG && c < 66) {
    int k = kseg * KSEG + koff;
    if (c < 64) v = tw[k] * w1[(size_t)k * 64 + c];
    else        v = wsc[(size_t)k * 2 + (c - 64)];
  }
  wcat[i] = f2bf(v);
}

// ===== k1: single-barrier MFMA GEMM, deep register prefetch, fp16 partial C =====
__global__ __launch_bounds__(256) void k1f(const float* __restrict__ hidden,
                                           const short* __restrict__ wcat,
                                           _Float16* __restrict__ part) {
  __shared__ short bs[WSEG];           // 32000 B
  const int tid  = threadIdx.x;
  const int bid  = blockIdx.x;
  const int tile = bid >> 2;           // 0..127
  const int kseg = bid & 3;
  const int k0   = kseg * KSEG;

  const int w    = tid >> 6;
  const int lane = tid & 63;
  const int ci   = lane & 15;
  const int g    = lane >> 4;
  const int kg   = g * 8;
  const int r0   = tile * BM + w * 16;

  // ---- 1) issue ALL B loads (oldest in vmcnt queue) ----
  const short* wseg = wcat + (size_t)kseg * WSEG;
  short8v breg[8];
#pragma unroll
  for (int i = 0; i < 7; ++i)
    breg[i] = *reinterpret_cast<const short8v*>(wseg + (size_t)(tid + 256 * i) * 8);
  if (tid < 208)
    breg[7] = *reinterpret_cast<const short8v*>(wseg + (size_t)(1792 + tid) * 8);

  // ---- 2) issue ALL A loads (12 x float4, independent, stay in flight) ----
  const float* aptr = hidden + (size_t)(r0 + ci) * H_DIM + k0 + kg;
  float4 abuf[12];
#pragma unroll
  for (int ks = 0; ks < 6; ++ks) {
    abuf[2 * ks]     = *reinterpret_cast<const float4*>(aptr + ks * 32);
    abuf[2 * ks + 1] = *reinterpret_cast<const float4*>(aptr + ks * 32 + 4);
  }

  // ---- 3) write B to LDS (consumes breg; compiler waits counted vmcnt) ----
#pragma unroll
  for (int i = 0; i < 7; ++i)
    *reinterpret_cast<short8v*>(&bs[(tid + 256 * i) * 8]) = breg[i];
  if (tid < 208)
    *reinterpret_cast<short8v*>(&bs[(1792 + tid) * 8]) = breg[7];
  __syncthreads();   // the ONLY barrier

  // ---- 4) convert A + MFMA from registers/LDS ----
  f32x4 acc[5];
#pragma unroll
  for (int nt = 0; nt < 5; ++nt) acc[nt] = (f32x4){0.f, 0.f, 0.f, 0.f};

#pragma unroll
  for (int ks = 0; ks < 6; ++ks) {
    const float4 a0 = abuf[2 * ks];
    const float4 a1 = abuf[2 * ks + 1];
    short8v av;
    av[0] = f2bf(a0.x); av[1] = f2bf(a0.y); av[2] = f2bf(a0.z); av[3] = f2bf(a0.w);
    av[4] = f2bf(a1.x); av[5] = f2bf(a1.y); av[6] = f2bf(a1.z); av[7] = f2bf(a1.w);
#pragma unroll
    for (int nt = 0; nt < 5; ++nt) {
      short8v bb = *reinterpret_cast<const short8v*>(&bs[(nt * 16 + ci) * KPAD + ks * 32 + kg]);
      acc[nt] = __builtin_amdgcn_mfma_f32_16x16x32_bf16(av, bb, acc[nt], 0, 0, 0);
    }
  }

  _Float16* pr = part + ((size_t)kseg * BS_TOK + r0) * PSTRIDE;
#pragma unroll
  for (int j = 0; j < 4; ++j) {
    int r = 4 * g + j;
#pragma unroll
    for (int nt = 0; nt < 4; ++nt)
      pr[r * PSTRIDE + nt * 16 + ci] = (_Float16)acc[nt][j];
    if (ci < 2) pr[r * PSTRIDE + 64 + ci] = (_Float16)acc[4][j];
  }
}

// ===== kB: fused partial-reduce + relu-MLP epilogue + prefix softmax =====
__global__ __launch_bounds__(256) void kB(const _Float16* __restrict__ part,
                                          const float* __restrict__ b1,
                                          const float* __restrict__ w2,
                                          const float* __restrict__ b2,
                                          const float* __restrict__ bsc,
                                          float* __restrict__ out) {
  __shared__ float lp[TOKB + 8][4];   // [logit, p0, p1, pad]
  const int tid  = threadIdx.x;
  const int t0   = blockIdx.x * TOKB;
  const int w    = tid >> 6;
  const int lane = tid & 63;
  const int ci   = lane & 15;
  const int grp  = lane >> 4;
  const int base = w * 4 + grp;       // 0..15 token-slot per pass

#pragma unroll
  for (int pass = 0; pass < 3; ++pass) {
    int slot = pass * 16 + base;
    if (slot < TOKB + 7) {
      int tt = min(t0 + slot, BS_TOK - 1);
      // batch the 4 independent seg loads
      h4 v[KSPLIT];
      float pv2[2] = {0.f, 0.f};
#pragma unroll
      for (int seg = 0; seg < KSPLIT; ++seg)
        v[seg] = *reinterpret_cast<const h4*>(
            part + ((size_t)seg * BS_TOK + tt) * PSTRIDE + 4 * ci);
      f32x4 s = (f32x4){0.f, 0.f, 0.f, 0.f};
#pragma unroll
      for (int seg = 0; seg < KSPLIT; ++seg) {
        s[0] += (float)v[seg][0]; s[1] += (float)v[seg][1];
        s[2] += (float)v[seg][2]; s[3] += (float)v[seg][3];
      }
      if (ci < 2) {
#pragma unroll
        for (int seg = 0; seg < KSPLIT; ++seg)
          pv2[0] += (float)part[((size_t)seg * BS_TOK + tt) * PSTRIDE + 64 + ci];
      }
      const float4 bb = *reinterpret_cast<const float4*>(b1 + 4 * ci);
      const float4 ww = *reinterpret_cast<const float4*>(w2 + 4 * ci);
      float r = fmaxf(s[0] + bb.x, 0.f) * ww.x + fmaxf(s[1] + bb.y, 0.f) * ww.y +
                fmaxf(s[2] + bb.z, 0.f) * ww.z + fmaxf(s[3] + bb.w, 0.f) * ww.w;
#pragma unroll
      for (int msk = 1; msk < 16; msk <<= 1) r += __shfl_xor(r, msk, 64);
      if (ci == 0) lp[slot][0] = r + b2[0];
      if (ci < 2)  lp[slot][1 + ci] = pv2[0];
    }
  }
  __syncthreads();

  if (tid < TOKB) {
    int t = t0 + tid;
    int s_ = t & (S_LEN - 1);
    int nmax = min(8, S_LEN - s_);
    float bs0 = bsc[0], bs1 = bsc[1];
    float m = lp[tid][0];
    float d = 1.f;
    float n0 = lp[tid][1], n1 = lp[tid][2];
    float o[16];
    o[0] = n0 + bs0; o[1] = n1 + bs1;
#pragma unroll
    for (int j = 1; j < 8; ++j) {
      if (j < nmax) {
        float L  = lp[tid + j][0];
        float nm = fmaxf(m, L);
        float sc = __expf(m - nm);
        float e  = __expf(L - nm);
        d  = d  * sc + e;
        n0 = n0 * sc + e * lp[tid + j][1];
        n1 = n1 * sc + e * lp[tid + j][2];
        m = nm;
      }
      float inv = 1.f / d;
      o[2 * j]     = n0 * inv + bs0;
      o[2 * j + 1] = n1 * inv + bs1;
    }
    float4* op = reinterpret_cast<float4*>(out + (size_t)t * 16);
#pragma unroll
    for (int i = 0; i < 4; ++i) op[i] = *reinterpret_cast<float4*>(&o[4 * i]);
  }
}

// ===== fallback path (small ws) =====

__global__ __launch_bounds__(256) void kprepS(const float* __restrict__ tw,
                                              const float* __restrict__ w1,
                                              const float* __restrict__ wsc,
                                              short* __restrict__ wcat) {
  int i = blockIdx.x * 256 + threadIdx.x;
  if (i >= NCOLS * H_DIM) return;
  int c = i / H_DIM, k = i - c * H_DIM;
  float v = 0.f;
  if (c < 64)       v = tw[k] * w1[k * 64 + c];
  else if (c == 64) v = wsc[k * 2 + 0];
  else if (c == 65) v = wsc[k * 2 + 1];
  wcat[i] = f2bf(v);
}

__global__ __launch_bounds__(256) void k1s(const float* __restrict__ hidden,
                                           const short* __restrict__ wcat,
                                           const float* __restrict__ b1,
                                           const float* __restrict__ w2,
                                           const float* __restrict__ b2,
                                           float* __restrict__ logit,
                                           float* __restrict__ pbuf) {
  __shared__ short as[64 * 72];
  __shared__ short bss[NCOLS * 72];
  const int tid  = threadIdx.x;
  const int t0   = blockIdx.x * 64;
  const int w    = tid >> 6;
  const int lane = tid & 63;
  const int ci   = lane & 15;
  const int kg   = (lane >> 4) * 8;
  const int arow = w * 16 + ci;

  f32x4 acc[5];
#pragma unroll
  for (int nt = 0; nt < 5; ++nt) acc[nt] = (f32x4){0.f, 0.f, 0.f, 0.f};

  for (int cc = 0; cc < H_DIM / 64; ++cc) {
    const int k0 = cc * 64;
    __syncthreads();
#pragma unroll
    for (int i = 0; i < 4; ++i) {
      int f = tid + 256 * i;
      int r = f >> 4, c4 = f & 15;
      const float4 v = *reinterpret_cast<const float4*>(
          hidden + (size_t)(t0 + r) * H_DIM + k0 + c4 * 4);
      short4v bv;
      bv[0] = f2bf(v.x); bv[1] = f2bf(v.y); bv[2] = f2bf(v.z); bv[3] = f2bf(v.w);
      *reinterpret_cast<short4v*>(&as[r * 72 + c4 * 4]) = bv;
    }
    for (int i = tid; i < NCOLS * 8; i += 256) {
      int r = i >> 3, c8 = i & 7;
      short8v v = *reinterpret_cast<const short8v*>(wcat + r * H_DIM + k0 + c8 * 8);
      *reinterpret_cast<short8v*>(&bss[r * 72 + c8 * 8]) = v;
    }
    __syncthreads();
#pragma unroll
    for (int ks = 0; ks < 64; ks += 32) {
      short8v a = *reinterpret_cast<const short8v*>(&as[arow * 72 + ks + kg]);
#pragma unroll
      for (int nt = 0; nt < 5; ++nt) {
        short8v bb = *reinterpret_cast<const short8v*>(&bss[(nt * 16 + ci) * 72 + ks + kg]);
        acc[nt] = __builtin_amdgcn_mfma_f32_16x16x32_bf16(a, bb, acc[nt], 0, 0, 0);
      }
    }
  }

  const int g = lane >> 4;
  float lg[4];
#pragma unroll
  for (int j = 0; j < 4; ++j) {
    float sacc = 0.f;
#pragma unroll
    for (int nt = 0; nt < 4; ++nt) {
      int c = nt * 16 + ci;
      float z = acc[nt][j] + b1[c];
      z = fmaxf(z, 0.f);
      sacc += z * w2[c];
    }
#pragma unroll
    for (int msk = 1; msk < 16; msk <<= 1) sacc += __shfl_xor(sacc, msk, 64);
    lg[j] = sacc;
  }
  const float b2v = b2[0];
#pragma unroll
  for (int j = 0; j < 4; ++j) {
    int rg = t0 + w * 16 + 4 * g + j;
    if (ci == 0) {
      logit[rg] = lg[j] + b2v;
      pbuf[rg * 2 + 0] = acc[4][j];
    } else if (ci == 1) {
      pbuf[rg * 2 + 1] = acc[4][j];
    }
  }
}

__global__ __launch_bounds__(256) void k3g(const float* __restrict__ logit,
                                           const float* __restrict__ pbuf,
                                           const float* __restrict__ bsc,
                                           float* __restrict__ out) {
  int t = blockIdx.x * 256 + threadIdx.x;
  int s = t & (S_LEN - 1);
  int nmax = min(8, S_LEN - s);
  float bs0 = bsc[0], bs1 = bsc[1];
  float m = logit[t];
  float d = 1.f;
  float n0 = pbuf[2 * t], n1 = pbuf[2 * t + 1];
  float o[16];
  o[0] = n0 + bs0; o[1] = n1 + bs1;
#pragma unroll
  for (int j = 1; j < 8; ++j) {
    if (j < nmax) {
      float L  = logit[t + j];
      float nm = fmaxf(m, L);
      float sc = __expf(m - nm);
      float e  = __expf(L - nm);
      d  = d  * sc + e;
      n0 = n0 * sc + e * pbuf[2 * (t + j)];
      n1 = n1 * sc + e * pbuf[2 * (t + j) + 1];
      m = nm;
    }
    float inv = 1.f / d;
    o[2 * j]     = n0 * inv + bs0;
    o[2 * j + 1] = n1 * inv + bs1;
  }
  float4* op = reinterpret_cast<float4*>(out + (size_t)t * 16);
#pragma unroll
  for (int i = 0; i < 4; ++i) op[i] = *reinterpret_cast<float4*>(&o[4 * i]);
}

// ===== launch =====

extern "C" void kernel_launch(void* const* d_in, const int* in_sizes, int n_in,
                              void* d_out, int out_size, void* d_ws, size_t ws_size,
                              hipStream_t stream) {
  const float* hidden = (const float*)d_in[0];
  const float* tw     = (const float*)d_in[1];
  const float* w1     = (const float*)d_in[2];
  const float* b1     = (const float*)d_in[3];
  const float* w2     = (const float*)d_in[4];
  const float* b2     = (const float*)d_in[5];
  const float* wsc    = (const float*)d_in[6];
  const float* bsc    = (const float*)d_in[7];
  float* out = (float*)d_out;
  char* ws = (char*)d_ws;

  const size_t part_bytes = (size_t)KSPLIT * BS_TOK * PSTRIDE * 2;  // 4,718,592
  const size_t wcat_bytes = (size_t)KSPLIT * WSEG * 2;              // 128,000
  const size_t need_fast  = part_bytes + wcat_bytes;

  if (ws_size >= need_fast) {
    _Float16* part = (_Float16*)ws;
    short* wcat    = (short*)(ws + part_bytes);
    kprep<<<(KSPLIT * WSEG + 255) / 256, 256, 0, stream>>>(tw, w1, wsc, wcat);
    k1f  <<<(BS_TOK / BM) * KSPLIT, 256, 0, stream>>>(hidden, wcat, part);
    kB   <<<BS_TOK / TOKB, 256, 0, stream>>>(part, b1, w2, b2, bsc, out);
  } else {
    short* wcat  = (short*)ws;
    float* logit = (float*)(ws + 131072);
    float* pbuf  = (float*)(ws + 131072 + 32768);
    kprepS<<<(NCOLS * H_DIM + 255) / 256, 256, 0, stream>>>(tw, w1, wsc, wcat);
    k1s<<<BS_TOK / 64, 256, 0, stream>>>(hidden, wcat, b1, w2, b2, logit, pbuf);
    k3g<<<BS_TOK / 256, 256, 0, stream>>>(logit, pbuf, bsc, out);
  }
}